// Round 4
// baseline (298.563 us; speedup 1.0000x reference)
//
#include <hip/hip_runtime.h>
#include <hip/hip_bf16.h>

// Problem constants
#define BATCH 128
#define CH    2
#define NN    256
#define DD    256
#define KTOT  131072          // CH*NN*DD
#define KHALF 128             // NN/2

#define KS    32              // k per stage (one MFMA K)
#define NTB   128             // cols per block (N half)
#define PITCH 40              // shorts per LDS row (80B: 16B-aligned, bank-stride 20 -> uniform)

typedef short bf16x8 __attribute__((ext_vector_type(8)));
typedef float f32x4  __attribute__((ext_vector_type(4)));

// 2 floats -> packed bf16 hi pair + packed bf16 lo pair (RNE, cvt_pk path)
__device__ __forceinline__ void hilo2(float a, float b, unsigned& hp, unsigned& lp) {
    union { __hip_bfloat162 v; unsigned u; } H, L;
    H.v = __float22bfloat162_rn(float2{a, b});
    hp = H.u;
    float2 hf = __bfloat1622float2(H.v);
    L.v = __float22bfloat162_rn(float2{a - hf.x, b - hf.y});
    lp = L.u;
}

// ---------------------------------------------------------------------------
// Split-K MFMA GEMM, fp32 emulated via bf16 hi/lo 3-pass (hh + hl + lh).
// Block = 256 threads (4 waves as 2M x 2N, wave tile 64x64), tile M=128 N=128.
// Register double-buffer: stage st+1 global loads issue BEFORE stage st's
// barriers -> full-stage latency hiding (loads to VGPR cross s_barrier).
// ---------------------------------------------------------------------------
template <int SLICES, bool ATOMIC>
__global__ __launch_bounds__(256, 2) void gemm_mfma(const float* __restrict__ x,
                                                    const float* __restrict__ W,
                                                    float* __restrict__ zout) {
    constexpr int KLEN = KTOT / SLICES;
    constexpr int NST  = KLEN / KS;
    constexpr int NBLK = SLICES * 2;

    __shared__ unsigned short Ah[128][PITCH], Al[128][PITCH];
    __shared__ unsigned short Bh[NTB][PITCH], Bl[NTB][PITCH];

    // XCD-aware decode: the nh-pair of a slice lands on one XCD (x L2 reuse)
    const int bid     = blockIdx.x;
    const int logical = (bid & 7) * (NBLK >> 3) + (bid >> 3);
    const int s       = logical >> 1;
    const int nh      = logical & 1;

    const int t  = threadIdx.x;
    const int k0 = s * KLEN;
    const int c  = k0 >> 16;           // channel plane (slice never crosses)
    const int nd_base = k0 & 65535;

    // staging maps: thread owns one A row-halfk and one B col-halfk
    const int ra = t & 127;            // A: batch row
    const int ha = t >> 7;             // A: k-half (16 floats)
    const int cb = t & 127;            // B: local col
    const int hb = t >> 7;             // B: k-half

    const float* xrow = &x[(size_t)ra * KTOT + k0 + 16 * ha];
    const float* wcol = &W[(size_t)(2 * (nd_base + 16 * hb) + c) * NN + nh * NTB + cb];

    auto loadr = [&](float* av, float* bv, int st) {
        const float* xp = xrow + st * KS;
        *(float4*)&av[0]  = *(const float4*)&xp[0];
        *(float4*)&av[4]  = *(const float4*)&xp[4];
        *(float4*)&av[8]  = *(const float4*)&xp[8];
        *(float4*)&av[12] = *(const float4*)&xp[12];
        const float* wp = wcol + (size_t)st * KS * 2 * NN;
#pragma unroll
        for (int i = 0; i < 16; ++i)
            bv[i] = wp[(size_t)i * 2 * NN];   // W row stride 2*NN (channel-interleaved)
    };

    auto writest = [&](const float* av, const float* bv) {
        uint4 H0, H1, L0, L1;
        hilo2(av[0],  av[1],  H0.x, L0.x); hilo2(av[2],  av[3],  H0.y, L0.y);
        hilo2(av[4],  av[5],  H0.z, L0.z); hilo2(av[6],  av[7],  H0.w, L0.w);
        hilo2(av[8],  av[9],  H1.x, L1.x); hilo2(av[10], av[11], H1.y, L1.y);
        hilo2(av[12], av[13], H1.z, L1.z); hilo2(av[14], av[15], H1.w, L1.w);
        *(uint4*)&Ah[ra][16 * ha]     = H0;
        *(uint4*)&Ah[ra][16 * ha + 8] = H1;
        *(uint4*)&Al[ra][16 * ha]     = L0;
        *(uint4*)&Al[ra][16 * ha + 8] = L1;
        hilo2(bv[0],  bv[1],  H0.x, L0.x); hilo2(bv[2],  bv[3],  H0.y, L0.y);
        hilo2(bv[4],  bv[5],  H0.z, L0.z); hilo2(bv[6],  bv[7],  H0.w, L0.w);
        hilo2(bv[8],  bv[9],  H1.x, L1.x); hilo2(bv[10], bv[11], H1.y, L1.y);
        hilo2(bv[12], bv[13], H1.z, L1.z); hilo2(bv[14], bv[15], H1.w, L1.w);
        *(uint4*)&Bh[cb][16 * hb]     = H0;
        *(uint4*)&Bh[cb][16 * hb + 8] = H1;
        *(uint4*)&Bl[cb][16 * hb]     = L0;
        *(uint4*)&Bl[cb][16 * hb + 8] = L1;
    };

    // compute maps
    const int lane = t & 63;
    const int wid  = t >> 6;
    const int wm   = (wid >> 1) * 64;
    const int wn   = (wid & 1) * 64;
    const int lr   = lane & 15;
    const int kq   = (lane >> 4) * 8;  // 8-k segment of the frag

    f32x4 acc[4][4] = {};

    auto compute = [&]() {
        bf16x8 a_h[4], a_l[4];
#pragma unroll
        for (int mt = 0; mt < 4; ++mt) {
            a_h[mt] = *(const bf16x8*)&Ah[wm + mt * 16 + lr][kq];
            a_l[mt] = *(const bf16x8*)&Al[wm + mt * 16 + lr][kq];
        }
#pragma unroll
        for (int nt = 0; nt < 4; ++nt) {
            bf16x8 b_h = *(const bf16x8*)&Bh[wn + nt * 16 + lr][kq];
            bf16x8 b_l = *(const bf16x8*)&Bl[wn + nt * 16 + lr][kq];
#pragma unroll
            for (int mt = 0; mt < 4; ++mt) {
                acc[mt][nt] = __builtin_amdgcn_mfma_f32_16x16x32_bf16(a_h[mt], b_h, acc[mt][nt], 0, 0, 0);
                acc[mt][nt] = __builtin_amdgcn_mfma_f32_16x16x32_bf16(a_h[mt], b_l, acc[mt][nt], 0, 0, 0);
                acc[mt][nt] = __builtin_amdgcn_mfma_f32_16x16x32_bf16(a_l[mt], b_h, acc[mt][nt], 0, 0, 0);
            }
        }
    };

    float avA[16], bvA[16], avB[16], bvB[16];
    loadr(avA, bvA, 0);
#pragma unroll
    for (int st = 0; st < NST; st += 2) {
        if (st + 1 < NST) loadr(avB, bvB, st + 1);   // in flight across barriers
        __syncthreads();                              // prev compute done
        writest(avA, bvA);
        __syncthreads();                              // stage visible
        compute();
        if (st + 2 < NST) loadr(avA, bvA, st + 2);
        __syncthreads();
        writest(avB, bvB);
        __syncthreads();
        compute();
    }

    // epilogue: C layout col=lane&15, row=(lane>>4)*4+reg  [verified round 2]
#pragma unroll
    for (int mt = 0; mt < 4; ++mt)
#pragma unroll
        for (int nt = 0; nt < 4; ++nt)
#pragma unroll
            for (int r = 0; r < 4; ++r) {
                const int row = wm + mt * 16 + (lane >> 4) * 4 + r;
                const int col = nh * NTB + wn + nt * 16 + lr;
                if (ATOMIC) atomicAdd(&zout[row * NN + col], acc[mt][nt][r]);
                else zout[(size_t)s * (BATCH * NN) + row * NN + col] = acc[mt][nt][r];
            }
}

// ---------------------------------------------------------------------------
// Stage-1 reduction: SLICES K-slices -> SLICES/32 groups.
// Grid = (SLICES/32) * BATCH blocks.
// ---------------------------------------------------------------------------
template <int SLICES>
__global__ __launch_bounds__(256) void reduce1(const float* __restrict__ part,
                                               float* __restrict__ part2) {
    constexpr int GROUPS = SLICES / 32;
    const int g = blockIdx.x % GROUPS;
    const int b = blockIdx.x / GROUPS;
    const int j = threadIdx.x;
    float v = 0.0f;
#pragma unroll
    for (int i = 0; i < 32; ++i)
        v += part[(size_t)(g * 32 + i) * (BATCH * NN) + b * NN + j];
    part2[(size_t)g * (BATCH * NN) + b * NN + j] = v;
}

// ---------------------------------------------------------------------------
// Final sum + median selection + stable compaction.
// ---------------------------------------------------------------------------
__global__ __launch_bounds__(256) void select_kernel(const float* __restrict__ p2, int ngroups,
                                                     int* __restrict__ idx_att,
                                                     int* __restrict__ idx_drp) {
    __shared__ float zv[NN];
    __shared__ int   flags[NN];
    const int b = blockIdx.x;
    const int j = threadIdx.x;
    float v = 0.0f;
    for (int g = 0; g < ngroups; ++g)
        v += p2[(size_t)g * (BATCH * NN) + b * NN + j];
    zv[j] = v;
    __syncthreads();
    int rank = 0;
    for (int i = 0; i < NN; ++i) {
        const float u = zv[i];
        rank += (u < v) || (u == v && i < j);
    }
    const int kept = (rank >= KHALF) ? 1 : 0;
    flags[j] = kept;
    __syncthreads();
    int pos = 0;
    for (int i = 0; i < j; ++i) pos += flags[i];
    if (kept) idx_att[b * KHALF + pos]       = j;
    else      idx_drp[b * KHALF + (j - pos)] = j;
}

// ---------------------------------------------------------------------------
// Gather: out[b,c,k,:] = x[b,c,att[k],:] + 1e-4 * x[b,c,drp[k],:]
// ---------------------------------------------------------------------------
__global__ __launch_bounds__(256) void gather_kernel(const float* __restrict__ x,
                                                     const int* __restrict__ idx_att,
                                                     const int* __restrict__ idx_drp,
                                                     float* __restrict__ out) {
    const int row  = blockIdx.x * 4 + (threadIdx.x >> 6);  // (b*2+c)*128+k
    const int lane = threadIdx.x & 63;
    const int k = row & 127;
    const int c = (row >> 7) & 1;
    const int b = row >> 8;
    const int ia = idx_att[b * KHALF + k];
    const int id = idx_drp[b * KHALF + k];
    const float4* pa = (const float4*)&x[((b * 2 + c) * NN + ia) * DD];
    const float4* pd = (const float4*)&x[((b * 2 + c) * NN + id) * DD];
    float4* po = (float4*)&out[(size_t)row * DD];
    const float4 a  = pa[lane];
    const float4 d4 = pd[lane];
    float4 o;
    o.x = a.x + 1e-4f * d4.x;
    o.y = a.y + 1e-4f * d4.y;
    o.z = a.z + 1e-4f * d4.z;
    o.w = a.w + 1e-4f * d4.w;
    po[lane] = o;
}

extern "C" void kernel_launch(void* const* d_in, const int* in_sizes, int n_in,
                              void* d_out, int out_size, void* d_ws, size_t ws_size,
                              hipStream_t stream) {
    const float* x = (const float*)d_in[0];
    const float* W = (const float*)d_in[1];
    float* out = (float*)d_out;

    const size_t zrow   = (size_t)BATCH * NN * sizeof(float);  // 128 KiB
    const size_t idxB   = (size_t)BATCH * KHALF * sizeof(int); // 64 KiB each
    const size_t pA     = 512 * zrow;                          // 64 MiB
    const size_t p2A    = 16 * zrow;                           //  2 MiB
    const size_t pB     = 256 * zrow;                          // 32 MiB
    const size_t p2B    = 8 * zrow;                            //  1 MiB

    if (ws_size >= pA + p2A + 2 * idxB) {
        float* part    = (float*)d_ws;
        float* part2   = (float*)((char*)d_ws + pA);
        int*   idx_att = (int*)((char*)d_ws + pA + p2A);
        int*   idx_drp = idx_att + BATCH * KHALF;
        gemm_mfma<512, false><<<1024, 256, 0, stream>>>(x, W, part);
        reduce1<512><<<16 * BATCH, 256, 0, stream>>>(part, part2);
        select_kernel<<<BATCH, 256, 0, stream>>>(part2, 16, idx_att, idx_drp);
        gather_kernel<<<BATCH * CH * KHALF / 4, 256, 0, stream>>>(x, idx_att, idx_drp, out);
    } else if (ws_size >= pB + p2B + 2 * idxB) {
        float* part    = (float*)d_ws;
        float* part2   = (float*)((char*)d_ws + pB);
        int*   idx_att = (int*)((char*)d_ws + pB + p2B);
        int*   idx_drp = idx_att + BATCH * KHALF;
        gemm_mfma<256, false><<<512, 256, 0, stream>>>(x, W, part);
        reduce1<256><<<8 * BATCH, 256, 0, stream>>>(part, part2);
        select_kernel<<<BATCH, 256, 0, stream>>>(part2, 8, idx_att, idx_drp);
        gather_kernel<<<BATCH * CH * KHALF / 4, 256, 0, stream>>>(x, idx_att, idx_drp, out);
    } else {
        float* z       = (float*)d_ws;
        int*   idx_att = (int*)((char*)d_ws + zrow);
        int*   idx_drp = idx_att + BATCH * KHALF;
        hipMemsetAsync(z, 0, zrow, stream);
        gemm_mfma<512, true><<<1024, 256, 0, stream>>>(x, W, z);
        select_kernel<<<BATCH, 256, 0, stream>>>(z, 1, idx_att, idx_drp);
        gather_kernel<<<BATCH * CH * KHALF / 4, 256, 0, stream>>>(x, idx_att, idx_drp, out);
    }
}